// Round 12
// baseline (403.426 us; speedup 1.0000x reference)
//
#include <hip/hip_runtime.h>
#include <hip/hip_bf16.h>

// Problem constants (LightConeAttention): B=2, T=6, H=16, W=16, C=256, NUM_HEADS=8
#define BB   2
#define TT   6
#define HH   16
#define WW   16
#define CC   256
#define NH   8
#define HD   32
#define NN   (TT*HH*WW)      // 1536
#define BN   (BB*NN)         // 3072
#define SCALE 0.17677669529663687f               // 1/sqrt(32)
#define SCALE_L2E (0.17677669529663687f * 1.4426950408889634f)  // fold log2e -> 2^x

// MEASUREMENT ROUND: each kernel body repeats REP times (idempotent writes,
// memory clobber per rep so the compiler re-executes loads/MFMAs). Purpose:
// lift each kernel above the 40us harness poison-fills so rocprof top-5
// finally shows per-kernel dur + counters. w_kernel = dur_us / REP.
#define REP 32

typedef __attribute__((ext_vector_type(8))) short bf16x8;
typedef __attribute__((ext_vector_type(4))) short bf16x4;
typedef __attribute__((ext_vector_type(4))) float f32x4;
typedef __attribute__((ext_vector_type(16))) float f32x16;

static __device__ inline short f2b(float x) {
    __hip_bfloat16 h = __float2bfloat16(x);
    return __builtin_bit_cast(short, h);
}

static __device__ inline float exp2_raw(float x) {   // 2^x via v_exp_f32
    float r;
    asm("v_exp_f32 %0, %1" : "=v"(r) : "v"(x));
    return r;
}

// ---------------------------------------------------------------------------
// Kernel 1: QKV projection (identical math to R11), body x REP.
// ---------------------------------------------------------------------------
__global__ __launch_bounds__(256) void gemm1_qkv(const float* __restrict__ x,
                                                 const float* __restrict__ Wqkv,
                                                 short* __restrict__ Qb,
                                                 short* __restrict__ Kb,
                                                 short* __restrict__ VT) {
    const int tid = threadIdx.x;
    const int w = tid >> 6, lane = tid & 63;
    const int g = lane >> 4, c16 = lane & 15;
    const int ct = blockIdx.x % 12;
    const int rg = blockIdx.x / 12;
    const int n0 = ct * 64;
    const int mw = rg * 64 + w * 16;

    __shared__ short wlds[64 * 256];
    char* const wbase = (char*)wlds;

    for (int rep = 0; rep < REP; ++rep) {
        // ---- stage W slice
        {
            const int n_l = tid & 63;
            const int kc  = tid >> 6;
            const int sw  = (n_l & 7) << 4;
            #pragma unroll
            for (int it = 0; it < 8; ++it) {
                const int k0s = it * 32 + kc * 8;
                const float* wp = Wqkv + (size_t)k0s * 768 + n0 + n_l;
                short t8[8];
                #pragma unroll
                for (int i = 0; i < 8; ++i) t8[i] = f2b(wp[(size_t)i * 768]);
                *(bf16x8*)(wbase + n_l * 512 + ((k0s * 2) ^ sw)) = *(bf16x8*)t8;
            }
        }
        __syncthreads();

        f32x4 acc[4] = {};
        #pragma unroll
        for (int ks = 0; ks < 8; ++ks) {
            const int k0 = ks * 32;
            const float* ap = x + (size_t)(mw + c16) * 256 + k0 + 8 * g;
            const float4 fa = *(const float4*)ap;
            const float4 fb = *(const float4*)(ap + 4);
            short ta[8] = { f2b(fa.x), f2b(fa.y), f2b(fa.z), f2b(fa.w),
                            f2b(fb.x), f2b(fb.y), f2b(fb.z), f2b(fb.w) };
            const bf16x8 a0 = *(bf16x8*)ta;
            #pragma unroll
            for (int ni = 0; ni < 4; ++ni) {
                const int n_l2 = ni * 16 + c16;
                const bf16x8 bfr = *(const bf16x8*)(wbase + n_l2 * 512 +
                                      ((ks * 64 + g * 16) ^ ((n_l2 & 7) << 4)));
                acc[ni] = __builtin_amdgcn_mfma_f32_16x16x32_bf16(a0, bfr, acc[ni], 0, 0, 0);
            }
        }
        const int sec = ct >> 2;
        const int b = mw >= NN;
        const int nbase = mw - b * NN;
        #pragma unroll
        for (int ni = 0; ni < 4; ++ni) {
            const int col = n0 + ni * 16;
            const int h  = (col >> 5) & 7;
            const int d0 = col & 31;
            const int bh = b * 8 + h;
            if (sec == 2) {
                short t4[4];
                #pragma unroll
                for (int r = 0; r < 4; ++r) t4[r] = f2b(acc[ni][r]);
                const int kt  = nbase >> 5;
                const int klo = (nbase & 16) + 4 * g;
                size_t off = ((size_t)((bh * 48 + kt) * 32) + d0 + c16) * 32 + klo;
                *(bf16x4*)(VT + off) = *(bf16x4*)t4;
            } else {
                short* dst = (sec == 0) ? Qb : Kb;
                const float sc = (sec == 0) ? SCALE_L2E : 1.f;
                #pragma unroll
                for (int r = 0; r < 4; ++r)
                    dst[((size_t)bh * NN + nbase + 4 * g + r) * 32 + d0 + c16] =
                        f2b(acc[ni][r] * sc);
            }
        }
        __syncthreads();                   // LDS reuse across reps
        asm volatile("" ::: "memory");     // force genuine re-execution
    }
}

// ---------------------------------------------------------------------------
// Kernel 2: 32x32 MFMA light-cone attention (identical math to R11), x REP.
// ---------------------------------------------------------------------------
__global__ __launch_bounds__(256) void attn_mfma32(const short* __restrict__ Qb,
                                                   const short* __restrict__ Kb,
                                                   const short* __restrict__ VT,
                                                   const float* __restrict__ Wo,
                                                   short* __restrict__ woT,
                                                   short* __restrict__ aob) {
    const int w    = threadIdx.x >> 6;
    const int lane = threadIdx.x & 63;
    const int l31  = lane & 31;
    const int gb   = lane >> 5;
    const int wq   = lane & 15;
    const int qh   = (lane >> 4) & 1;
    const int task = blockIdx.x;
    const int qt = task % 48, bh = task / 48;
    const int tqp = qt >> 4, hq = qt & 15;
    const int tq_a = 2 * tqp, tq_b = tq_a + 1;

    // side job (once): pack Wo^T to bf16 (blocks 0..31)
    if (blockIdx.x < 32) {
        const int idx = blockIdx.x * 256 + threadIdx.x;
        const int k0 = (idx & 31) * 8;
        const int n  = idx >> 5;
        short t[8];
        #pragma unroll
        for (int j = 0; j < 8; ++j) t[j] = f2b(Wo[(size_t)(k0 + j) * 256 + n]);
        *(bf16x8*)(woT + (size_t)n * 256 + k0) = *(bf16x8*)t;
    }

    __shared__ float sm_l[4][64];
    __shared__ float sm_acc[4][64][17];

    for (int rep = 0; rep < REP; ++rep) {
        const int tq_l = qh ? tq_b : tq_a;
        const int qn   = tq_l * 256 + hq * 16 + wq;
        const short* QBH = Qb + (size_t)bh * NN * 32;
        const bf16x8 qf0 = *(const bf16x8*)(QBH + (size_t)qn * 32 + 8 * gb);
        const bf16x8 qf1 = *(const bf16x8*)(QBH + (size_t)qn * 32 + 16 + 8 * gb);

        int dwv[8];
        #pragma unroll
        for (int i = 0; i < 8; ++i) {
            int kl = (i & 3) + 8 * (i >> 2) + 4 * gb;
            int d = kl - wq; dwv[i] = d < 0 ? -d : d;
        }

        const int tqm_a = tq_a ? tq_a : 1;
        int ntiles = 0;
        int cst[6], h20[6], rtav[6], rtbv[6];
        #pragma unroll
        for (int tk = 0; tk < 6; ++tk) {
            int rb = 1 + (15 * (tq_b - tk)) / tq_b;
            int ra = (tk <= tq_a) ? (1 + (15 * (tq_a - tk)) / tqm_a) : -1;
            int lo = hq - rb; lo = lo < 0 ? 0 : lo;
            int hi = hq + rb; hi = hi > 15 ? 15 : hi;
            int c  = (tk <= tq_b) ? ((hi >> 1) - (lo >> 1) + 1) : 0;
            cst[tk] = ntiles; h20[tk] = lo >> 1; rtav[tk] = ra; rtbv[tk] = rb;
            ntiles += c;
        }

        auto tiledesc = [&](int t, int& kb, int& ra, int& rb) {
            int sc_ = cst[0], sh_ = h20[0], sa_ = rtav[0], sb_ = rtbv[0], st_ = 0;
            #pragma unroll
            for (int tk = 1; tk < 6; ++tk) {
                const bool sel = (tk <= tq_b) && (t >= cst[tk]);
                sc_ = sel ? cst[tk]  : sc_;
                sh_ = sel ? h20[tk]  : sh_;
                sa_ = sel ? rtav[tk] : sa_;
                sb_ = sel ? rtbv[tk] : sb_;
                st_ = sel ? tk       : st_;
            }
            kb = st_ * 256 + (sh_ + (t - sc_)) * 32;
            ra = sa_; rb = sb_;
        };

        const short* KBH = Kb + (size_t)bh * NN * 32;
        const short* VBH = VT + (size_t)bh * 48 * 32 * 32;

        f32x16 acc, zf16;
        #pragma unroll
        for (int r = 0; r < 16; ++r) { acc[r] = 0.f; zf16[r] = 0.f; }
        float l_run = 0.f;

        int pi = w;
        int kb = 0, ra = -1, rb = -1;
        bf16x8 kf0c = {}, kf1c = {}, vf0c = {}, vf1c = {};
        if (pi < ntiles) {
            tiledesc(pi, kb, ra, rb);
            kf0c = *(const bf16x8*)(KBH + (size_t)(kb + l31) * 32 + 8 * gb);
            kf1c = *(const bf16x8*)(KBH + (size_t)(kb + l31) * 32 + 16 + 8 * gb);
            vf0c = *(const bf16x8*)(VBH + (size_t)((kb >> 5) * 32 + l31) * 32 + 8 * gb);
            vf1c = *(const bf16x8*)(VBH + (size_t)((kb >> 5) * 32 + l31) * 32 + 16 + 8 * gb);
        }
        while (pi < ntiles) {
            const int pn = pi + 4;
            int kbn, ran, rbn;
            tiledesc(pn < ntiles ? pn : pi, kbn, ran, rbn);
            const bf16x8 kf0n = *(const bf16x8*)(KBH + (size_t)(kbn + l31) * 32 + 8 * gb);
            const bf16x8 kf1n = *(const bf16x8*)(KBH + (size_t)(kbn + l31) * 32 + 16 + 8 * gb);
            const bf16x8 vf0n = *(const bf16x8*)(VBH + (size_t)((kbn >> 5) * 32 + l31) * 32 + 8 * gb);
            const bf16x8 vf1n = *(const bf16x8*)(VBH + (size_t)((kbn >> 5) * 32 + l31) * 32 + 16 + 8 * gb);

            const int rt_l = qh ? rb : ra;
            const int hk2 = (kb >> 5) & 7;
            const int t0 = 2 * hk2 - hq;
            const int dh0 = t0 < 0 ? -t0 : t0;
            const int t1 = t0 + 1;
            const int dh1 = t1 < 0 ? -t1 : t1;
            const bool A0 = dh0 <= rt_l, A1 = dh1 <= rt_l;
            bool dok[8];
            #pragma unroll
            for (int i = 0; i < 8; ++i) dok[i] = dwv[i] <= rt_l;

            f32x16 s = __builtin_amdgcn_mfma_f32_32x32x16_bf16(kf0c, qf0, zf16, 0, 0, 0);
            s = __builtin_amdgcn_mfma_f32_32x32x16_bf16(kf1c, qf1, s, 0, 0, 0);

            float p[16];
            #pragma unroll
            for (int r = 0; r < 16; ++r) {
                const bool ok = (r < 8 ? A0 : A1) && dok[r & 7];
                p[r] = ok ? exp2_raw(s[r]) : 0.f;
            }
            float ps = (((p[0] + p[1]) + (p[2] + p[3])) + ((p[4] + p[5]) + (p[6] + p[7])))
                     + (((p[8] + p[9]) + (p[10] + p[11])) + ((p[12] + p[13]) + (p[14] + p[15])));
            l_run += ps;

            unsigned u[8];
            #pragma unroll
            for (int j = 0; j < 8; ++j)
                asm("v_cvt_pk_bf16_f32 %0, %1, %2" : "=v"(u[j]) : "v"(p[2 * j]), "v"(p[2 * j + 1]));
            asm volatile("v_permlane32_swap_b32 %0, %1" : "+v"(u[0]), "+v"(u[2]));
            asm volatile("v_permlane32_swap_b32 %0, %1" : "+v"(u[1]), "+v"(u[3]));
            asm volatile("v_permlane32_swap_b32 %0, %1" : "+v"(u[4]), "+v"(u[6]));
            asm volatile("v_permlane32_swap_b32 %0, %1" : "+v"(u[5]), "+v"(u[7]));
            const int4 b1i = { (int)u[0], (int)u[1], (int)u[2], (int)u[3] };
            const int4 b2i = { (int)u[4], (int)u[5], (int)u[6], (int)u[7] };
            const bf16x8 pb1 = __builtin_bit_cast(bf16x8, b1i);
            const bf16x8 pb2 = __builtin_bit_cast(bf16x8, b2i);

            acc = __builtin_amdgcn_mfma_f32_32x32x16_bf16(vf0c, pb1, acc, 0, 0, 0);
            acc = __builtin_amdgcn_mfma_f32_32x32x16_bf16(vf1c, pb2, acc, 0, 0, 0);

            pi = pn; kb = kbn; ra = ran; rb = rbn;
            kf0c = kf0n; kf1c = kf1n; vf0c = vf0n; vf1c = vf1n;
        }

        sm_l[w][lane] = l_run;
        #pragma unroll
        for (int r = 0; r < 16; ++r) sm_acc[w][lane][r] = acc[r];
        __syncthreads();
        {
            const float lt = (sm_l[0][l31] + sm_l[0][l31 + 32])
                           + (sm_l[1][l31] + sm_l[1][l31 + 32])
                           + (sm_l[2][l31] + sm_l[2][l31 + 32])
                           + (sm_l[3][l31] + sm_l[3][l31 + 32]);
            const float inv = 1.f / lt;
            short* op = aob + ((size_t)(bh >> 3) * NN + qn) * CC + (bh & 7) * 32;
            short t4[4];
            #pragma unroll
            for (int s2 = 0; s2 < 4; ++s2) {
                const int r = 4 * w + s2;
                const float a = sm_acc[0][lane][r] + sm_acc[1][lane][r]
                              + sm_acc[2][lane][r] + sm_acc[3][lane][r];
                t4[s2] = f2b(a * inv);
            }
            *(bf16x4*)(op + 8 * w + 4 * gb) = *(bf16x4*)t4;
        }
        __syncthreads();                   // sm reuse across reps
        asm volatile("" ::: "memory");
    }
}

// ---------------------------------------------------------------------------
// Kernel 3: output projection + bias (identical math to R11), body x REP.
// ---------------------------------------------------------------------------
__global__ __launch_bounds__(256) void gemm2_out(const short* __restrict__ aob,
                                                 const short* __restrict__ woT,
                                                 const float* __restrict__ bias,
                                                 float* __restrict__ out) {
    const int w = threadIdx.x >> 6, lane = threadIdx.x & 63;
    const int g = lane >> 4, c16 = lane & 15;
    const int n0 = (blockIdx.x & 3) * 64;
    const int mw = (blockIdx.x >> 2) * 64 + w * 16;
    for (int rep = 0; rep < REP; ++rep) {
        f32x4 acc[4] = {};
        #pragma unroll
        for (int ks = 0; ks < 8; ++ks) {
            const int k0 = ks * 32;
            const bf16x8 a0 = *(const bf16x8*)(aob + (size_t)(mw + c16) * 256 + k0 + g * 8);
            #pragma unroll
            for (int ni = 0; ni < 4; ++ni) {
                const bf16x8 bfr = *(const bf16x8*)(woT + (size_t)(n0 + ni * 16 + c16) * 256 + k0 + g * 8);
                acc[ni] = __builtin_amdgcn_mfma_f32_16x16x32_bf16(a0, bfr, acc[ni], 0, 0, 0);
            }
        }
        #pragma unroll
        for (int ni = 0; ni < 4; ++ni) {
            const int col = n0 + ni * 16 + c16;
            const float bv = bias[col];
            #pragma unroll
            for (int r = 0; r < 4; ++r)
                out[(size_t)(mw + 4 * g + r) * 256 + col] = acc[ni][r] + bv;
        }
        asm volatile("" ::: "memory");
    }
}

// ---------------------------------------------------------------------------
extern "C" void kernel_launch(void* const* d_in, const int* in_sizes, int n_in,
                              void* d_out, int out_size, void* d_ws, size_t ws_size,
                              hipStream_t stream) {
    const float* x    = (const float*)d_in[0];
    const float* Wqkv = (const float*)d_in[1];
    const float* Wo   = (const float*)d_in[2];
    const float* bo   = (const float*)d_in[3];
    float* out = (float*)d_out;

    short* Qb  = (short*)d_ws;                   // 786432 bf16
    short* Kb  = Qb  + 786432;                   // 786432
    short* VT  = Kb  + 786432;                   // 786432
    short* aob = VT  + 786432;                   // 786432
    short* woT = aob + 786432;                   // 65536

    gemm1_qkv<<<576, 256, 0, stream>>>(x, Wqkv, Qb, Kb, VT);
    attn_mfma32<<<768, 256, 0, stream>>>(Qb, Kb, VT, Wo, woT, aob);
    gemm2_out<<<192, 256, 0, stream>>>(aob, woT, bo, out);
}

// Round 13
// 57.745 us; speedup vs baseline: 6.9864x; 6.9864x over previous
//
#include <hip/hip_runtime.h>
#include <hip/hip_bf16.h>

// Problem constants (LightConeAttention): B=2, T=6, H=16, W=16, C=256, NUM_HEADS=8
#define BB   2
#define TT   6
#define HH   16
#define WW   16
#define CC   256
#define NH   8
#define HD   32
#define NN   (TT*HH*WW)      // 1536
#define BN   (BB*NN)         // 3072
#define SCALE 0.17677669529663687f               // 1/sqrt(32)
#define SCALE_L2E (0.17677669529663687f * 1.4426950408889634f)  // fold log2e -> 2^x

typedef __attribute__((ext_vector_type(8))) short bf16x8;
typedef __attribute__((ext_vector_type(4))) short bf16x4;
typedef __attribute__((ext_vector_type(4))) float f32x4;
typedef __attribute__((ext_vector_type(16))) float f32x16;

static __device__ inline short f2b(float x) {
    __hip_bfloat16 h = __float2bfloat16(x);
    return __builtin_bit_cast(short, h);
}

static __device__ inline float exp2_raw(float x) {   // 2^x via v_exp_f32
    float r;
    asm("v_exp_f32 %0, %1" : "=v"(r) : "v"(x));
    return r;
}

// ---------------------------------------------------------------------------
// Kernel 1: QKV projection (unchanged from R11). W-tile staged once per block
// in LDS (bf16, XOR swizzle). 576 blocks x 4 waves; 16-row x 64-col wave-tile.
// Epilogue: Q (pre-scaled by SCALE*log2e) / K -> [bh][n][32];
//           V -> VT [bh][kt][d][k32].
// ---------------------------------------------------------------------------
__global__ __launch_bounds__(256) void gemm1_qkv(const float* __restrict__ x,
                                                 const float* __restrict__ Wqkv,
                                                 short* __restrict__ Qb,
                                                 short* __restrict__ Kb,
                                                 short* __restrict__ VT) {
    const int tid = threadIdx.x;
    const int w = tid >> 6, lane = tid & 63;
    const int g = lane >> 4, c16 = lane & 15;
    const int ct = blockIdx.x % 12;
    const int rg = blockIdx.x / 12;
    const int n0 = ct * 64;
    const int mw = rg * 64 + w * 16;

    __shared__ short wlds[64 * 256];
    char* const wbase = (char*)wlds;

    {
        const int n_l = tid & 63;
        const int kc  = tid >> 6;
        const int sw  = (n_l & 7) << 4;
        #pragma unroll
        for (int it = 0; it < 8; ++it) {
            const int k0s = it * 32 + kc * 8;
            const float* wp = Wqkv + (size_t)k0s * 768 + n0 + n_l;
            short t8[8];
            #pragma unroll
            for (int i = 0; i < 8; ++i) t8[i] = f2b(wp[(size_t)i * 768]);
            *(bf16x8*)(wbase + n_l * 512 + ((k0s * 2) ^ sw)) = *(bf16x8*)t8;
        }
    }
    __syncthreads();

    f32x4 acc[4] = {};
    #pragma unroll
    for (int ks = 0; ks < 8; ++ks) {
        const int k0 = ks * 32;
        const float* ap = x + (size_t)(mw + c16) * 256 + k0 + 8 * g;
        const float4 fa = *(const float4*)ap;
        const float4 fb = *(const float4*)(ap + 4);
        short ta[8] = { f2b(fa.x), f2b(fa.y), f2b(fa.z), f2b(fa.w),
                        f2b(fb.x), f2b(fb.y), f2b(fb.z), f2b(fb.w) };
        const bf16x8 a0 = *(bf16x8*)ta;
        #pragma unroll
        for (int ni = 0; ni < 4; ++ni) {
            const int n_l2 = ni * 16 + c16;
            const bf16x8 bfr = *(const bf16x8*)(wbase + n_l2 * 512 +
                                  ((ks * 64 + g * 16) ^ ((n_l2 & 7) << 4)));
            acc[ni] = __builtin_amdgcn_mfma_f32_16x16x32_bf16(a0, bfr, acc[ni], 0, 0, 0);
        }
    }
    const int sec = ct >> 2;               // 0:Q 1:K 2:V
    const int b = mw >= NN;
    const int nbase = mw - b * NN;
    #pragma unroll
    for (int ni = 0; ni < 4; ++ni) {
        const int col = n0 + ni * 16;
        const int h  = (col >> 5) & 7;
        const int d0 = col & 31;
        const int bh = b * 8 + h;
        if (sec == 2) {
            short t4[4];
            #pragma unroll
            for (int r = 0; r < 4; ++r) t4[r] = f2b(acc[ni][r]);
            const int kt  = nbase >> 5;
            const int klo = (nbase & 16) + 4 * g;
            size_t off = ((size_t)((bh * 48 + kt) * 32) + d0 + c16) * 32 + klo;
            *(bf16x4*)(VT + off) = *(bf16x4*)t4;
        } else {
            short* dst = (sec == 0) ? Qb : Kb;
            const float sc = (sec == 0) ? SCALE_L2E : 1.f;
            #pragma unroll
            for (int r = 0; r < 4; ++r)
                dst[((size_t)bh * NN + nbase + 4 * g + r) * 32 + d0 + c16] =
                    f2b(acc[ni][r] * sc);
        }
    }
}

// ---------------------------------------------------------------------------
// Kernel 2: 32x32 MFMA light-cone attention. R13 change: 8 WAVES per block
// (512 threads), tiles round-robin stride 8 -> 24 waves/CU (75% occupancy
// cap) vs R11's 12 (37.5%). R12 counters showed VALUBusy 64% @ occupancy
// 22.7% -> issue stalls from dependency chains; doubling resident waves
// covers them. Merge is 8-way; waves 0..3 reduce + write. Math identical.
// ---------------------------------------------------------------------------
__global__ __launch_bounds__(512, 6) void attn_mfma32(const short* __restrict__ Qb,
                                                      const short* __restrict__ Kb,
                                                      const short* __restrict__ VT,
                                                      const float* __restrict__ Wo,
                                                      short* __restrict__ woT,
                                                      short* __restrict__ aob) {
    const int w    = threadIdx.x >> 6;     // 0..7
    const int lane = threadIdx.x & 63;
    const int l31  = lane & 31;
    const int gb   = lane >> 5;
    const int wq   = lane & 15;
    const int qh   = (lane >> 4) & 1;      // 0: tq_a half, 1: tq_b half
    const int task = blockIdx.x;           // 0..767
    const int qt = task % 48, bh = task / 48;
    const int tqp = qt >> 4, hq = qt & 15;
    const int tq_a = 2 * tqp, tq_b = tq_a + 1;

    // side job: pack Wo^T to bf16 (blocks 0..15, 512 threads each = 8192)
    if (blockIdx.x < 16) {
        const int idx = blockIdx.x * 512 + threadIdx.x;
        const int k0 = (idx & 31) * 8;
        const int n  = idx >> 5;
        short t[8];
        #pragma unroll
        for (int j = 0; j < 8; ++j) t[j] = f2b(Wo[(size_t)(k0 + j) * 256 + n]);
        *(bf16x8*)(woT + (size_t)n * 256 + k0) = *(bf16x8*)t;
    }

    __shared__ float sm_l[8][64];
    __shared__ float sm_acc[8][64][17];

    const int tq_l = qh ? tq_b : tq_a;
    const int qn   = tq_l * 256 + hq * 16 + wq;
    const short* QBH = Qb + (size_t)bh * NN * 32;
    const bf16x8 qf0 = *(const bf16x8*)(QBH + (size_t)qn * 32 + 8 * gb);
    const bf16x8 qf1 = *(const bf16x8*)(QBH + (size_t)qn * 32 + 16 + 8 * gb);

    int dwv[8];
    #pragma unroll
    for (int i = 0; i < 8; ++i) {
        int kl = (i & 3) + 8 * (i >> 2) + 4 * gb;
        int d = kl - wq; dwv[i] = d < 0 ? -d : d;
    }

    const int tqm_a = tq_a ? tq_a : 1;
    int ntiles = 0;
    int cst[6], h20[6], rtav[6], rtbv[6];
    #pragma unroll
    for (int tk = 0; tk < 6; ++tk) {
        int rb = 1 + (15 * (tq_b - tk)) / tq_b;
        int ra = (tk <= tq_a) ? (1 + (15 * (tq_a - tk)) / tqm_a) : -1;
        int lo = hq - rb; lo = lo < 0 ? 0 : lo;
        int hi = hq + rb; hi = hi > 15 ? 15 : hi;
        int c  = (tk <= tq_b) ? ((hi >> 1) - (lo >> 1) + 1) : 0;
        cst[tk] = ntiles; h20[tk] = lo >> 1; rtav[tk] = ra; rtbv[tk] = rb;
        ntiles += c;
    }

    auto tiledesc = [&](int t, int& kb, int& ra, int& rb) {
        int sc_ = cst[0], sh_ = h20[0], sa_ = rtav[0], sb_ = rtbv[0], st_ = 0;
        #pragma unroll
        for (int tk = 1; tk < 6; ++tk) {
            const bool sel = (tk <= tq_b) && (t >= cst[tk]);
            sc_ = sel ? cst[tk]  : sc_;
            sh_ = sel ? h20[tk]  : sh_;
            sa_ = sel ? rtav[tk] : sa_;
            sb_ = sel ? rtbv[tk] : sb_;
            st_ = sel ? tk       : st_;
        }
        kb = st_ * 256 + (sh_ + (t - sc_)) * 32;
        ra = sa_; rb = sb_;
    };

    const short* KBH = Kb + (size_t)bh * NN * 32;
    const short* VBH = VT + (size_t)bh * 48 * 32 * 32;

    f32x16 acc, zf16;
    #pragma unroll
    for (int r = 0; r < 16; ++r) { acc[r] = 0.f; zf16[r] = 0.f; }
    float l_run = 0.f;

    int pi = w;                            // stride 8 across waves
    int kb = 0, ra = -1, rb = -1;
    bf16x8 kf0c = {}, kf1c = {}, vf0c = {}, vf1c = {};
    if (pi < ntiles) {
        tiledesc(pi, kb, ra, rb);
        kf0c = *(const bf16x8*)(KBH + (size_t)(kb + l31) * 32 + 8 * gb);
        kf1c = *(const bf16x8*)(KBH + (size_t)(kb + l31) * 32 + 16 + 8 * gb);
        vf0c = *(const bf16x8*)(VBH + (size_t)((kb >> 5) * 32 + l31) * 32 + 8 * gb);
        vf1c = *(const bf16x8*)(VBH + (size_t)((kb >> 5) * 32 + l31) * 32 + 16 + 8 * gb);
    }
    while (pi < ntiles) {
        const int pn = pi + 8;
        int kbn, ran, rbn;
        tiledesc(pn < ntiles ? pn : pi, kbn, ran, rbn);
        const bf16x8 kf0n = *(const bf16x8*)(KBH + (size_t)(kbn + l31) * 32 + 8 * gb);
        const bf16x8 kf1n = *(const bf16x8*)(KBH + (size_t)(kbn + l31) * 32 + 16 + 8 * gb);
        const bf16x8 vf0n = *(const bf16x8*)(VBH + (size_t)((kbn >> 5) * 32 + l31) * 32 + 8 * gb);
        const bf16x8 vf1n = *(const bf16x8*)(VBH + (size_t)((kbn >> 5) * 32 + l31) * 32 + 16 + 8 * gb);

        const int rt_l = qh ? rb : ra;
        const int hk2 = (kb >> 5) & 7;
        const int t0 = 2 * hk2 - hq;
        const int dh0 = t0 < 0 ? -t0 : t0;
        const int t1 = t0 + 1;
        const int dh1 = t1 < 0 ? -t1 : t1;
        const bool A0 = dh0 <= rt_l, A1 = dh1 <= rt_l;
        bool dok[8];
        #pragma unroll
        for (int i = 0; i < 8; ++i) dok[i] = dwv[i] <= rt_l;

        f32x16 s = __builtin_amdgcn_mfma_f32_32x32x16_bf16(kf0c, qf0, zf16, 0, 0, 0);
        s = __builtin_amdgcn_mfma_f32_32x32x16_bf16(kf1c, qf1, s, 0, 0, 0);

        float p[16];
        #pragma unroll
        for (int r = 0; r < 16; ++r) {
            const bool ok = (r < 8 ? A0 : A1) && dok[r & 7];
            p[r] = ok ? exp2_raw(s[r]) : 0.f;   // Q pre-scaled by log2e
        }
        float ps = (((p[0] + p[1]) + (p[2] + p[3])) + ((p[4] + p[5]) + (p[6] + p[7])))
                 + (((p[8] + p[9]) + (p[10] + p[11])) + ((p[12] + p[13]) + (p[14] + p[15])));
        ps += __shfl_xor(ps, 32);
        l_run += ps;

        unsigned u[8];
        #pragma unroll
        for (int j = 0; j < 8; ++j)
            asm("v_cvt_pk_bf16_f32 %0, %1, %2" : "=v"(u[j]) : "v"(p[2 * j]), "v"(p[2 * j + 1]));
        asm volatile("v_permlane32_swap_b32 %0, %1" : "+v"(u[0]), "+v"(u[2]));
        asm volatile("v_permlane32_swap_b32 %0, %1" : "+v"(u[1]), "+v"(u[3]));
        asm volatile("v_permlane32_swap_b32 %0, %1" : "+v"(u[4]), "+v"(u[6]));
        asm volatile("v_permlane32_swap_b32 %0, %1" : "+v"(u[5]), "+v"(u[7]));
        const int4 b1i = { (int)u[0], (int)u[1], (int)u[2], (int)u[3] };
        const int4 b2i = { (int)u[4], (int)u[5], (int)u[6], (int)u[7] };
        const bf16x8 pb1 = __builtin_bit_cast(bf16x8, b1i);
        const bf16x8 pb2 = __builtin_bit_cast(bf16x8, b2i);

        acc = __builtin_amdgcn_mfma_f32_32x32x16_bf16(vf0c, pb1, acc, 0, 0, 0);
        acc = __builtin_amdgcn_mfma_f32_32x32x16_bf16(vf1c, pb2, acc, 0, 0, 0);

        pi = pn; kb = kbn; ra = ran; rb = rbn;
        kf0c = kf0n; kf1c = kf1n; vf0c = vf0n; vf1c = vf1n;
    }

    // 8-way merge: l_run already cross-gb summed (shfl); waves 0..3 reduce.
    sm_l[w][lane] = l_run;
    #pragma unroll
    for (int r = 0; r < 16; ++r) sm_acc[w][lane][r] = acc[r];
    __syncthreads();
    if (w < 4) {
        float lt = 0.f;
        #pragma unroll
        for (int ww = 0; ww < 8; ++ww) lt += sm_l[ww][l31];
        const float inv = 1.f / lt;
        short* op = aob + ((size_t)(bh >> 3) * NN + qn) * CC + (bh & 7) * 32;
        short t4[4];
        #pragma unroll
        for (int s2 = 0; s2 < 4; ++s2) {
            const int r = 4 * w + s2;       // d = 8w + 4gb + s2
            float a = 0.f;
            #pragma unroll
            for (int ww = 0; ww < 8; ++ww) a += sm_acc[ww][lane][r];
            t4[s2] = f2b(a * inv);
        }
        *(bf16x4*)(op + 8 * w + 4 * gb) = *(bf16x4*)t4;
    }
}

// ---------------------------------------------------------------------------
// Kernel 3: output projection + bias (unchanged from R11). Wo pre-packed bf16.
// ---------------------------------------------------------------------------
__global__ __launch_bounds__(256) void gemm2_out(const short* __restrict__ aob,
                                                 const short* __restrict__ woT,
                                                 const float* __restrict__ bias,
                                                 float* __restrict__ out) {
    const int w = threadIdx.x >> 6, lane = threadIdx.x & 63;
    const int g = lane >> 4, c16 = lane & 15;
    const int n0 = (blockIdx.x & 3) * 64;
    const int mw = (blockIdx.x >> 2) * 64 + w * 16;
    f32x4 acc[4] = {};
    #pragma unroll
    for (int ks = 0; ks < 8; ++ks) {
        const int k0 = ks * 32;
        const bf16x8 a0 = *(const bf16x8*)(aob + (size_t)(mw + c16) * 256 + k0 + g * 8);
        #pragma unroll
        for (int ni = 0; ni < 4; ++ni) {
            const bf16x8 bfr = *(const bf16x8*)(woT + (size_t)(n0 + ni * 16 + c16) * 256 + k0 + g * 8);
            acc[ni] = __builtin_amdgcn_mfma_f32_16x16x32_bf16(a0, bfr, acc[ni], 0, 0, 0);
        }
    }
    #pragma unroll
    for (int ni = 0; ni < 4; ++ni) {
        const int col = n0 + ni * 16 + c16;
        const float bv = bias[col];
        #pragma unroll
        for (int r = 0; r < 4; ++r)
            out[(size_t)(mw + 4 * g + r) * 256 + col] = acc[ni][r] + bv;
    }
}

// ---------------------------------------------------------------------------
extern "C" void kernel_launch(void* const* d_in, const int* in_sizes, int n_in,
                              void* d_out, int out_size, void* d_ws, size_t ws_size,
                              hipStream_t stream) {
    const float* x    = (const float*)d_in[0];
    const float* Wqkv = (const float*)d_in[1];
    const float* Wo   = (const float*)d_in[2];
    const float* bo   = (const float*)d_in[3];
    float* out = (float*)d_out;

    short* Qb  = (short*)d_ws;                   // 786432 bf16
    short* Kb  = Qb  + 786432;                   // 786432
    short* VT  = Kb  + 786432;                   // 786432
    short* aob = VT  + 786432;                   // 786432
    short* woT = aob + 786432;                   // 65536

    gemm1_qkv<<<576, 256, 0, stream>>>(x, Wqkv, Qb, Kb, VT);
    attn_mfma32<<<768, 512, 0, stream>>>(Qb, Kb, VT, Wo, woT, aob);
    gemm2_out<<<192, 256, 0, stream>>>(aob, woT, bo, out);
}

// Round 14
// 41.546 us; speedup vs baseline: 9.7104x; 1.3899x over previous
//
#include <hip/hip_runtime.h>
#include <hip/hip_bf16.h>

// Problem constants (LightConeAttention): B=2, T=6, H=16, W=16, C=256, NUM_HEADS=8
#define BB   2
#define TT   6
#define HH   16
#define WW   16
#define CC   256
#define NH   8
#define HD   32
#define NN   (TT*HH*WW)      // 1536
#define BN   (BB*NN)         // 3072
#define SCALE 0.17677669529663687f               // 1/sqrt(32)
#define SCALE_L2E (0.17677669529663687f * 1.4426950408889634f)  // fold log2e -> 2^x

typedef __attribute__((ext_vector_type(8))) short bf16x8;
typedef __attribute__((ext_vector_type(4))) short bf16x4;
typedef __attribute__((ext_vector_type(4))) float f32x4;
typedef __attribute__((ext_vector_type(16))) float f32x16;

static __device__ inline short f2b(float x) {
    __hip_bfloat16 h = __float2bfloat16(x);
    return __builtin_bit_cast(short, h);
}

static __device__ inline float exp2_raw(float x) {   // 2^x via v_exp_f32
    float r;
    asm("v_exp_f32 %0, %1" : "=v"(r) : "v"(x));
    return r;
}

// ---------------------------------------------------------------------------
// Kernel 1: QKV projection (R11 structure, proven 35.1us total). W-tile staged
// once per block in LDS (bf16, XOR swizzle). 576 blocks x 4 waves.
// Epilogue: Q (pre-scaled by SCALE*log2e) / K -> [bh][n][32];
//           V -> VT [bh][kt][d][k32].
// ---------------------------------------------------------------------------
__global__ __launch_bounds__(256) void gemm1_qkv(const float* __restrict__ x,
                                                 const float* __restrict__ Wqkv,
                                                 short* __restrict__ Qb,
                                                 short* __restrict__ Kb,
                                                 short* __restrict__ VT) {
    const int tid = threadIdx.x;
    const int w = tid >> 6, lane = tid & 63;
    const int g = lane >> 4, c16 = lane & 15;
    const int ct = blockIdx.x % 12;
    const int rg = blockIdx.x / 12;
    const int n0 = ct * 64;
    const int mw = rg * 64 + w * 16;

    __shared__ short wlds[64 * 256];
    char* const wbase = (char*)wlds;

    {
        const int n_l = tid & 63;
        const int kc  = tid >> 6;
        const int sw  = (n_l & 7) << 4;
        #pragma unroll
        for (int it = 0; it < 8; ++it) {
            const int k0s = it * 32 + kc * 8;
            const float* wp = Wqkv + (size_t)k0s * 768 + n0 + n_l;
            short t8[8];
            #pragma unroll
            for (int i = 0; i < 8; ++i) t8[i] = f2b(wp[(size_t)i * 768]);
            *(bf16x8*)(wbase + n_l * 512 + ((k0s * 2) ^ sw)) = *(bf16x8*)t8;
        }
    }
    __syncthreads();

    f32x4 acc[4] = {};
    #pragma unroll
    for (int ks = 0; ks < 8; ++ks) {
        const int k0 = ks * 32;
        const float* ap = x + (size_t)(mw + c16) * 256 + k0 + 8 * g;
        const float4 fa = *(const float4*)ap;
        const float4 fb = *(const float4*)(ap + 4);
        short ta[8] = { f2b(fa.x), f2b(fa.y), f2b(fa.z), f2b(fa.w),
                        f2b(fb.x), f2b(fb.y), f2b(fb.z), f2b(fb.w) };
        const bf16x8 a0 = *(bf16x8*)ta;
        #pragma unroll
        for (int ni = 0; ni < 4; ++ni) {
            const int n_l2 = ni * 16 + c16;
            const bf16x8 bfr = *(const bf16x8*)(wbase + n_l2 * 512 +
                                  ((ks * 64 + g * 16) ^ ((n_l2 & 7) << 4)));
            acc[ni] = __builtin_amdgcn_mfma_f32_16x16x32_bf16(a0, bfr, acc[ni], 0, 0, 0);
        }
    }
    const int sec = ct >> 2;               // 0:Q 1:K 2:V
    const int b = mw >= NN;
    const int nbase = mw - b * NN;
    #pragma unroll
    for (int ni = 0; ni < 4; ++ni) {
        const int col = n0 + ni * 16;
        const int h  = (col >> 5) & 7;
        const int d0 = col & 31;
        const int bh = b * 8 + h;
        if (sec == 2) {
            short t4[4];
            #pragma unroll
            for (int r = 0; r < 4; ++r) t4[r] = f2b(acc[ni][r]);
            const int kt  = nbase >> 5;
            const int klo = (nbase & 16) + 4 * g;
            size_t off = ((size_t)((bh * 48 + kt) * 32) + d0 + c16) * 32 + klo;
            *(bf16x4*)(VT + off) = *(bf16x4*)t4;
        } else {
            short* dst = (sec == 0) ? Qb : Kb;
            const float sc = (sec == 0) ? SCALE_L2E : 1.f;
            #pragma unroll
            for (int r = 0; r < 4; ++r)
                dst[((size_t)bh * NN + nbase + 4 * g + r) * 32 + d0 + c16] =
                    f2b(acc[ni][r] * sc);
        }
    }
}

// ---------------------------------------------------------------------------
// Kernel 2: 32x32 MFMA light-cone attention. R14: back to 256-thread blocks
// (R13's (512,6) launch bound forced 40-VGPR spills, FETCH 12->57MB).
// Occupancy is grid-limited (768 blocks / 256 CU = 12 waves/CU), so the
// VALU dependency stalls (R12: VALUBusy 64%) are attacked with in-wave ILP:
// each wave processes a PAIR of tiles (2w, 2w+1), step 8 — two independent
// QK->exp->cvt chains interleaved, PV into SPLIT accumulators (two 2-chains
// instead of one 4-chain). Sentinel tiles (rt=-1 -> p==0) keep the loop
// uniform; next-pair prefetch. Math identical to R11.
// ---------------------------------------------------------------------------
__global__ __launch_bounds__(256) void attn_mfma32(const short* __restrict__ Qb,
                                                   const short* __restrict__ Kb,
                                                   const short* __restrict__ VT,
                                                   const float* __restrict__ Wo,
                                                   short* __restrict__ woT,
                                                   short* __restrict__ aob) {
    const int w    = threadIdx.x >> 6;
    const int lane = threadIdx.x & 63;
    const int l31  = lane & 31;
    const int gb   = lane >> 5;
    const int wq   = lane & 15;
    const int qh   = (lane >> 4) & 1;      // 0: tq_a half, 1: tq_b half
    const int task = blockIdx.x;           // 0..767
    const int qt = task % 48, bh = task / 48;
    const int tqp = qt >> 4, hq = qt & 15;
    const int tq_a = 2 * tqp, tq_b = tq_a + 1;

    // side job: pack Wo^T to bf16 (blocks 0..31)
    if (blockIdx.x < 32) {
        const int idx = blockIdx.x * 256 + threadIdx.x;
        const int k0 = (idx & 31) * 8;
        const int n  = idx >> 5;
        short t[8];
        #pragma unroll
        for (int j = 0; j < 8; ++j) t[j] = f2b(Wo[(size_t)(k0 + j) * 256 + n]);
        *(bf16x8*)(woT + (size_t)n * 256 + k0) = *(bf16x8*)t;
    }

    __shared__ float sm_l[4][64];
    __shared__ float sm_acc[4][64][17];

    const int tq_l = qh ? tq_b : tq_a;
    const int qn   = tq_l * 256 + hq * 16 + wq;
    const short* QBH = Qb + (size_t)bh * NN * 32;
    const bf16x8 qf0 = *(const bf16x8*)(QBH + (size_t)qn * 32 + 8 * gb);
    const bf16x8 qf1 = *(const bf16x8*)(QBH + (size_t)qn * 32 + 16 + 8 * gb);

    int dwv[8];
    #pragma unroll
    for (int i = 0; i < 8; ++i) {
        int kl = (i & 3) + 8 * (i >> 2) + 4 * gb;
        int d = kl - wq; dwv[i] = d < 0 ? -d : d;
    }

    const int tqm_a = tq_a ? tq_a : 1;
    int ntiles = 0;
    int cst[6], h20[6], rtav[6], rtbv[6];
    #pragma unroll
    for (int tk = 0; tk < 6; ++tk) {
        int rb = 1 + (15 * (tq_b - tk)) / tq_b;
        int ra = (tk <= tq_a) ? (1 + (15 * (tq_a - tk)) / tqm_a) : -1;
        int lo = hq - rb; lo = lo < 0 ? 0 : lo;
        int hi = hq + rb; hi = hi > 15 ? 15 : hi;
        int c  = (tk <= tq_b) ? ((hi >> 1) - (lo >> 1) + 1) : 0;
        cst[tk] = ntiles; h20[tk] = lo >> 1; rtav[tk] = ra; rtbv[tk] = rb;
        ntiles += c;
    }

    // descriptor with sentinel for t >= ntiles (rt=-1 -> exact no-op tile)
    auto tiledesc = [&](int t, int& kb, int& ra, int& rb) {
        if (t >= ntiles) { kb = 0; ra = -1; rb = -1; return; }
        int sc_ = cst[0], sh_ = h20[0], sa_ = rtav[0], sb_ = rtbv[0], st_ = 0;
        #pragma unroll
        for (int tk = 1; tk < 6; ++tk) {
            const bool sel = (tk <= tq_b) && (t >= cst[tk]);
            sc_ = sel ? cst[tk]  : sc_;
            sh_ = sel ? h20[tk]  : sh_;
            sa_ = sel ? rtav[tk] : sa_;
            sb_ = sel ? rtbv[tk] : sb_;
            st_ = sel ? tk       : st_;
        }
        kb = st_ * 256 + (sh_ + (t - sc_)) * 32;
        ra = sa_; rb = sb_;
    };

    const short* KBH = Kb + (size_t)bh * NN * 32;
    const short* VBH = VT + (size_t)bh * 48 * 32 * 32;

    #define LOADK0(kb) (*(const bf16x8*)(KBH + (size_t)((kb) + l31) * 32 + 8 * gb))
    #define LOADK1(kb) (*(const bf16x8*)(KBH + (size_t)((kb) + l31) * 32 + 16 + 8 * gb))
    #define LOADV0(kb) (*(const bf16x8*)(VBH + (size_t)(((kb) >> 5) * 32 + l31) * 32 + 8 * gb))
    #define LOADV1(kb) (*(const bf16x8*)(VBH + (size_t)(((kb) >> 5) * 32 + l31) * 32 + 16 + 8 * gb))

    f32x16 accA, accB, zf16;
    #pragma unroll
    for (int r = 0; r < 16; ++r) { accA[r] = 0.f; accB[r] = 0.f; zf16[r] = 0.f; }
    float l_run = 0.f;

    int t0 = 2 * w;
    int kbA, raA, rbA, kbB, raB, rbB;
    bf16x8 kf0A = {}, kf1A = {}, vf0A = {}, vf1A = {};
    bf16x8 kf0B = {}, kf1B = {}, vf0B = {}, vf1B = {};
    if (t0 < ntiles) {
        tiledesc(t0, kbA, raA, rbA);
        tiledesc(t0 + 1, kbB, raB, rbB);
        kf0A = LOADK0(kbA); kf1A = LOADK1(kbA); vf0A = LOADV0(kbA); vf1A = LOADV1(kbA);
        kf0B = LOADK0(kbB); kf1B = LOADK1(kbB); vf0B = LOADV0(kbB); vf1B = LOADV1(kbB);
    }
    while (t0 < ntiles) {
        const int tn = t0 + 8;
        // prefetch next pair (sentinel-safe addresses)
        int kbA2, raA2, rbA2, kbB2, raB2, rbB2;
        tiledesc(tn, kbA2, raA2, rbA2);
        tiledesc(tn + 1, kbB2, raB2, rbB2);
        const bf16x8 kf0A2 = LOADK0(kbA2), kf1A2 = LOADK1(kbA2);
        const bf16x8 vf0A2 = LOADV0(kbA2), vf1A2 = LOADV1(kbA2);
        const bf16x8 kf0B2 = LOADK0(kbB2), kf1B2 = LOADK1(kbB2);
        const bf16x8 vf0B2 = LOADV0(kbB2), vf1B2 = LOADV1(kbB2);

        // --- masks (register-only, both tiles)
        const int rtA = qh ? rbA : raA;
        const int rtB = qh ? rbB : raB;
        const int hA = ((kbA >> 5) & 7) * 2 - hq;
        const int hB = ((kbB >> 5) & 7) * 2 - hq;
        const int dA0 = hA < 0 ? -hA : hA, dA1 = hA + 1 < 0 ? -(hA + 1) : hA + 1;
        const int dB0 = hB < 0 ? -hB : hB, dB1 = hB + 1 < 0 ? -(hB + 1) : hB + 1;
        const bool A0 = dA0 <= rtA, A1 = dA1 <= rtA;
        const bool B0 = dB0 <= rtB, B1 = dB1 <= rtB;
        bool dokA[8], dokB[8];
        #pragma unroll
        for (int i = 0; i < 8; ++i) { dokA[i] = dwv[i] <= rtA; dokB[i] = dwv[i] <= rtB; }

        // --- two independent QK chains
        f32x16 sA = __builtin_amdgcn_mfma_f32_32x32x16_bf16(kf0A, qf0, zf16, 0, 0, 0);
        f32x16 sB = __builtin_amdgcn_mfma_f32_32x32x16_bf16(kf0B, qf0, zf16, 0, 0, 0);
        sA = __builtin_amdgcn_mfma_f32_32x32x16_bf16(kf1A, qf1, sA, 0, 0, 0);
        sB = __builtin_amdgcn_mfma_f32_32x32x16_bf16(kf1B, qf1, sB, 0, 0, 0);

        float pA[16], pB[16];
        #pragma unroll
        for (int r = 0; r < 16; ++r) {
            const bool okA = (r < 8 ? A0 : A1) && dokA[r & 7];
            const bool okB = (r < 8 ? B0 : B1) && dokB[r & 7];
            pA[r] = okA ? exp2_raw(sA[r]) : 0.f;   // Q pre-scaled by log2e
            pB[r] = okB ? exp2_raw(sB[r]) : 0.f;
        }
        float psA = (((pA[0] + pA[1]) + (pA[2] + pA[3])) + ((pA[4] + pA[5]) + (pA[6] + pA[7])))
                  + (((pA[8] + pA[9]) + (pA[10] + pA[11])) + ((pA[12] + pA[13]) + (pA[14] + pA[15])));
        float psB = (((pB[0] + pB[1]) + (pB[2] + pB[3])) + ((pB[4] + pB[5]) + (pB[6] + pB[7])))
                  + (((pB[8] + pB[9]) + (pB[10] + pB[11])) + ((pB[12] + pB[13]) + (pB[14] + pB[15])));
        l_run += psA + psB;

        unsigned uA[8], uB[8];
        #pragma unroll
        for (int j = 0; j < 8; ++j) {
            asm("v_cvt_pk_bf16_f32 %0, %1, %2" : "=v"(uA[j]) : "v"(pA[2 * j]), "v"(pA[2 * j + 1]));
            asm("v_cvt_pk_bf16_f32 %0, %1, %2" : "=v"(uB[j]) : "v"(pB[2 * j]), "v"(pB[2 * j + 1]));
        }
        asm volatile("v_permlane32_swap_b32 %0, %1" : "+v"(uA[0]), "+v"(uA[2]));
        asm volatile("v_permlane32_swap_b32 %0, %1" : "+v"(uA[1]), "+v"(uA[3]));
        asm volatile("v_permlane32_swap_b32 %0, %1" : "+v"(uA[4]), "+v"(uA[6]));
        asm volatile("v_permlane32_swap_b32 %0, %1" : "+v"(uA[5]), "+v"(uA[7]));
        asm volatile("v_permlane32_swap_b32 %0, %1" : "+v"(uB[0]), "+v"(uB[2]));
        asm volatile("v_permlane32_swap_b32 %0, %1" : "+v"(uB[1]), "+v"(uB[3]));
        asm volatile("v_permlane32_swap_b32 %0, %1" : "+v"(uB[4]), "+v"(uB[6]));
        asm volatile("v_permlane32_swap_b32 %0, %1" : "+v"(uB[5]), "+v"(uB[7]));
        const int4 a1i = { (int)uA[0], (int)uA[1], (int)uA[2], (int)uA[3] };
        const int4 a2i = { (int)uA[4], (int)uA[5], (int)uA[6], (int)uA[7] };
        const int4 b1i = { (int)uB[0], (int)uB[1], (int)uB[2], (int)uB[3] };
        const int4 b2i = { (int)uB[4], (int)uB[5], (int)uB[6], (int)uB[7] };
        const bf16x8 pbA1 = __builtin_bit_cast(bf16x8, a1i);
        const bf16x8 pbA2 = __builtin_bit_cast(bf16x8, a2i);
        const bf16x8 pbB1 = __builtin_bit_cast(bf16x8, b1i);
        const bf16x8 pbB2 = __builtin_bit_cast(bf16x8, b2i);

        // split accumulators: two independent PV 2-chains
        accA = __builtin_amdgcn_mfma_f32_32x32x16_bf16(vf0A, pbA1, accA, 0, 0, 0);
        accB = __builtin_amdgcn_mfma_f32_32x32x16_bf16(vf0B, pbB1, accB, 0, 0, 0);
        accA = __builtin_amdgcn_mfma_f32_32x32x16_bf16(vf1A, pbA2, accA, 0, 0, 0);
        accB = __builtin_amdgcn_mfma_f32_32x32x16_bf16(vf1B, pbB2, accB, 0, 0, 0);

        t0 = tn;
        kbA = kbA2; raA = raA2; rbA = rbA2; kbB = kbB2; raB = raB2; rbB = rbB2;
        kf0A = kf0A2; kf1A = kf1A2; vf0A = vf0A2; vf1A = vf1A2;
        kf0B = kf0B2; kf1B = kf1B2; vf0B = vf0B2; vf1B = vf1B2;
    }

    // merge (R11 scheme): all 4 waves write their d-quarter
    sm_l[w][lane] = l_run;
    #pragma unroll
    for (int r = 0; r < 16; ++r) sm_acc[w][lane][r] = accA[r] + accB[r];
    __syncthreads();
    {
        const float lt = (sm_l[0][l31] + sm_l[0][l31 + 32])
                       + (sm_l[1][l31] + sm_l[1][l31 + 32])
                       + (sm_l[2][l31] + sm_l[2][l31 + 32])
                       + (sm_l[3][l31] + sm_l[3][l31 + 32]);
        const float inv = 1.f / lt;
        short* op = aob + ((size_t)(bh >> 3) * NN + qn) * CC + (bh & 7) * 32;
        short t4[4];
        #pragma unroll
        for (int s2 = 0; s2 < 4; ++s2) {
            const int r = 4 * w + s2;       // d = 8w + 4gb + s2
            const float a = sm_acc[0][lane][r] + sm_acc[1][lane][r]
                          + sm_acc[2][lane][r] + sm_acc[3][lane][r];
            t4[s2] = f2b(a * inv);
        }
        *(bf16x4*)(op + 8 * w + 4 * gb) = *(bf16x4*)t4;
    }
    #undef LOADK0
    #undef LOADK1
    #undef LOADV0
    #undef LOADV1
}

// ---------------------------------------------------------------------------
// Kernel 3: output projection + bias (unchanged). Wo pre-packed bf16.
// ---------------------------------------------------------------------------
__global__ __launch_bounds__(256) void gemm2_out(const short* __restrict__ aob,
                                                 const short* __restrict__ woT,
                                                 const float* __restrict__ bias,
                                                 float* __restrict__ out) {
    const int w = threadIdx.x >> 6, lane = threadIdx.x & 63;
    const int g = lane >> 4, c16 = lane & 15;
    const int n0 = (blockIdx.x & 3) * 64;
    const int mw = (blockIdx.x >> 2) * 64 + w * 16;
    f32x4 acc[4] = {};
    #pragma unroll
    for (int ks = 0; ks < 8; ++ks) {
        const int k0 = ks * 32;
        const bf16x8 a0 = *(const bf16x8*)(aob + (size_t)(mw + c16) * 256 + k0 + g * 8);
        #pragma unroll
        for (int ni = 0; ni < 4; ++ni) {
            const bf16x8 bfr = *(const bf16x8*)(woT + (size_t)(n0 + ni * 16 + c16) * 256 + k0 + g * 8);
            acc[ni] = __builtin_amdgcn_mfma_f32_16x16x32_bf16(a0, bfr, acc[ni], 0, 0, 0);
        }
    }
    #pragma unroll
    for (int ni = 0; ni < 4; ++ni) {
        const int col = n0 + ni * 16 + c16;
        const float bv = bias[col];
        #pragma unroll
        for (int r = 0; r < 4; ++r)
            out[(size_t)(mw + 4 * g + r) * 256 + col] = acc[ni][r] + bv;
    }
}

// ---------------------------------------------------------------------------
extern "C" void kernel_launch(void* const* d_in, const int* in_sizes, int n_in,
                              void* d_out, int out_size, void* d_ws, size_t ws_size,
                              hipStream_t stream) {
    const float* x    = (const float*)d_in[0];
    const float* Wqkv = (const float*)d_in[1];
    const float* Wo   = (const float*)d_in[2];
    const float* bo   = (const float*)d_in[3];
    float* out = (float*)d_out;

    short* Qb  = (short*)d_ws;                   // 786432 bf16
    short* Kb  = Qb  + 786432;                   // 786432
    short* VT  = Kb  + 786432;                   // 786432
    short* aob = VT  + 786432;                   // 786432
    short* woT = aob + 786432;                   // 65536

    gemm1_qkv<<<576, 256, 0, stream>>>(x, Wqkv, Qb, Kb, VT);
    attn_mfma32<<<768, 256, 0, stream>>>(Qb, Kb, VT, Wo, woT, aob);
    gemm2_out<<<192, 256, 0, stream>>>(aob, woT, bo, out);
}

// Round 15
// 35.282 us; speedup vs baseline: 11.4345x; 1.1775x over previous
//
#include <hip/hip_runtime.h>
#include <hip/hip_bf16.h>

// Problem constants (LightConeAttention): B=2, T=6, H=16, W=16, C=256, NUM_HEADS=8
#define BB   2
#define TT   6
#define HH   16
#define WW   16
#define CC   256
#define NH   8
#define HD   32
#define NN   (TT*HH*WW)      // 1536
#define BN   (BB*NN)         // 3072
#define SCALE 0.17677669529663687f               // 1/sqrt(32)
#define SCALE_L2E (0.17677669529663687f * 1.4426950408889634f)  // fold log2e -> 2^x

typedef __attribute__((ext_vector_type(8))) short bf16x8;
typedef __attribute__((ext_vector_type(4))) short bf16x4;
typedef __attribute__((ext_vector_type(4))) float f32x4;
typedef __attribute__((ext_vector_type(16))) float f32x16;

static __device__ inline short f2b(float x) {
    __hip_bfloat16 h = __float2bfloat16(x);
    return __builtin_bit_cast(short, h);
}

static __device__ inline float exp2_raw(float x) {   // 2^x via v_exp_f32
    float r;
    asm("v_exp_f32 %0, %1" : "=v"(r) : "v"(x));
    return r;
}

// ---------------------------------------------------------------------------
// Kernel 1: QKV projection (R11 — best measured). W-tile staged once per
// block in LDS (bf16, XOR swizzle: stage ds_write_b128 and fragment
// ds_read_b128 both conflict-free). 576 blocks x 4 waves; 16-row x 64-col
// wave-tile; the block's 4 waves share the col-tile.
// Epilogue: Q (pre-scaled by SCALE*log2e) / K -> [bh][n][32];
//           V -> VT [bh][kt][d][k32].
// ---------------------------------------------------------------------------
__global__ __launch_bounds__(256) void gemm1_qkv(const float* __restrict__ x,
                                                 const float* __restrict__ Wqkv,
                                                 short* __restrict__ Qb,
                                                 short* __restrict__ Kb,
                                                 short* __restrict__ VT) {
    const int tid = threadIdx.x;
    const int w = tid >> 6, lane = tid & 63;
    const int g = lane >> 4, c16 = lane & 15;
    const int ct = blockIdx.x % 12;
    const int rg = blockIdx.x / 12;
    const int n0 = ct * 64;
    const int mw = rg * 64 + w * 16;

    __shared__ short wlds[64 * 256];
    char* const wbase = (char*)wlds;

    {
        const int n_l = tid & 63;
        const int kc  = tid >> 6;
        const int sw  = (n_l & 7) << 4;
        #pragma unroll
        for (int it = 0; it < 8; ++it) {
            const int k0s = it * 32 + kc * 8;
            const float* wp = Wqkv + (size_t)k0s * 768 + n0 + n_l;
            short t8[8];
            #pragma unroll
            for (int i = 0; i < 8; ++i) t8[i] = f2b(wp[(size_t)i * 768]);
            *(bf16x8*)(wbase + n_l * 512 + ((k0s * 2) ^ sw)) = *(bf16x8*)t8;
        }
    }
    __syncthreads();

    f32x4 acc[4] = {};
    #pragma unroll
    for (int ks = 0; ks < 8; ++ks) {
        const int k0 = ks * 32;
        const float* ap = x + (size_t)(mw + c16) * 256 + k0 + 8 * g;
        const float4 fa = *(const float4*)ap;
        const float4 fb = *(const float4*)(ap + 4);
        short ta[8] = { f2b(fa.x), f2b(fa.y), f2b(fa.z), f2b(fa.w),
                        f2b(fb.x), f2b(fb.y), f2b(fb.z), f2b(fb.w) };
        const bf16x8 a0 = *(bf16x8*)ta;
        #pragma unroll
        for (int ni = 0; ni < 4; ++ni) {
            const int n_l2 = ni * 16 + c16;
            const bf16x8 bfr = *(const bf16x8*)(wbase + n_l2 * 512 +
                                  ((ks * 64 + g * 16) ^ ((n_l2 & 7) << 4)));
            acc[ni] = __builtin_amdgcn_mfma_f32_16x16x32_bf16(a0, bfr, acc[ni], 0, 0, 0);
        }
    }
    const int sec = ct >> 2;               // 0:Q 1:K 2:V
    const int b = mw >= NN;
    const int nbase = mw - b * NN;
    #pragma unroll
    for (int ni = 0; ni < 4; ++ni) {
        const int col = n0 + ni * 16;
        const int h  = (col >> 5) & 7;
        const int d0 = col & 31;
        const int bh = b * 8 + h;
        if (sec == 2) {
            short t4[4];
            #pragma unroll
            for (int r = 0; r < 4; ++r) t4[r] = f2b(acc[ni][r]);
            const int kt  = nbase >> 5;
            const int klo = (nbase & 16) + 4 * g;
            size_t off = ((size_t)((bh * 48 + kt) * 32) + d0 + c16) * 32 + klo;
            *(bf16x4*)(VT + off) = *(bf16x4*)t4;
        } else {
            short* dst = (sec == 0) ? Qb : Kb;
            const float sc = (sec == 0) ? SCALE_L2E : 1.f;
            #pragma unroll
            for (int r = 0; r < 4; ++r)
                dst[((size_t)bh * NN + nbase + 4 * g + r) * 32 + d0 + c16] =
                    f2b(acc[ni][r] * sc);
        }
    }
}

// ---------------------------------------------------------------------------
// Kernel 2: 32x32 MFMA light-cone attention (R11 — best measured: one tile
// per wave per iteration, stride 4, next-tile prefetch, inline register
// compare-select tile descriptors, no online max — |s| ~ O(1) bounds exp).
// R13 (8-wave blocks w/ launch-bound cap) spilled; R14 (pair-ILP) inflated
// register pressure; both regressed — this structure is the measured optimum.
// Blocks 0..31 also pack Wo -> woT bf16 for kernel 3.
// ---------------------------------------------------------------------------
__global__ __launch_bounds__(256) void attn_mfma32(const short* __restrict__ Qb,
                                                   const short* __restrict__ Kb,
                                                   const short* __restrict__ VT,
                                                   const float* __restrict__ Wo,
                                                   short* __restrict__ woT,
                                                   short* __restrict__ aob) {
    const int w    = threadIdx.x >> 6;
    const int lane = threadIdx.x & 63;
    const int l31  = lane & 31;
    const int gb   = lane >> 5;
    const int wq   = lane & 15;
    const int qh   = (lane >> 4) & 1;      // 0: tq_a half, 1: tq_b half
    const int task = blockIdx.x;           // 0..767
    const int qt = task % 48, bh = task / 48;
    const int tqp = qt >> 4, hq = qt & 15;
    const int tq_a = 2 * tqp, tq_b = tq_a + 1;

    // side job: pack Wo^T to bf16 (blocks 0..31)
    if (blockIdx.x < 32) {
        const int idx = blockIdx.x * 256 + threadIdx.x;
        const int k0 = (idx & 31) * 8;
        const int n  = idx >> 5;
        short t[8];
        #pragma unroll
        for (int j = 0; j < 8; ++j) t[j] = f2b(Wo[(size_t)(k0 + j) * 256 + n]);
        *(bf16x8*)(woT + (size_t)n * 256 + k0) = *(bf16x8*)t;
    }

    __shared__ float sm_l[4][64];
    __shared__ float sm_acc[4][64][17];

    const int tq_l = qh ? tq_b : tq_a;
    const int qn   = tq_l * 256 + hq * 16 + wq;
    const short* QBH = Qb + (size_t)bh * NN * 32;
    const bf16x8 qf0 = *(const bf16x8*)(QBH + (size_t)qn * 32 + 8 * gb);
    const bf16x8 qf1 = *(const bf16x8*)(QBH + (size_t)qn * 32 + 16 + 8 * gb);

    int dwv[8];
    #pragma unroll
    for (int i = 0; i < 8; ++i) {
        int kl = (i & 3) + 8 * (i >> 2) + 4 * gb;
        int d = kl - wq; dwv[i] = d < 0 ? -d : d;
    }

    const int tqm_a = tq_a ? tq_a : 1;
    int ntiles = 0;
    int cst[6], h20[6], rtav[6], rtbv[6];
    #pragma unroll
    for (int tk = 0; tk < 6; ++tk) {
        int rb = 1 + (15 * (tq_b - tk)) / tq_b;
        int ra = (tk <= tq_a) ? (1 + (15 * (tq_a - tk)) / tqm_a) : -1;
        int lo = hq - rb; lo = lo < 0 ? 0 : lo;
        int hi = hq + rb; hi = hi > 15 ? 15 : hi;
        int c  = (tk <= tq_b) ? ((hi >> 1) - (lo >> 1) + 1) : 0;
        cst[tk] = ntiles; h20[tk] = lo >> 1; rtav[tk] = ra; rtbv[tk] = rb;
        ntiles += c;
    }

    // inline per-tile descriptor: register compare-select chain (no LDS)
    auto tiledesc = [&](int t, int& kb, int& ra, int& rb) {
        int sc_ = cst[0], sh_ = h20[0], sa_ = rtav[0], sb_ = rtbv[0], st_ = 0;
        #pragma unroll
        for (int tk = 1; tk < 6; ++tk) {
            const bool sel = (tk <= tq_b) && (t >= cst[tk]);
            sc_ = sel ? cst[tk]  : sc_;
            sh_ = sel ? h20[tk]  : sh_;
            sa_ = sel ? rtav[tk] : sa_;
            sb_ = sel ? rtbv[tk] : sb_;
            st_ = sel ? tk       : st_;
        }
        kb = st_ * 256 + (sh_ + (t - sc_)) * 32;
        ra = sa_; rb = sb_;
    };

    const short* KBH = Kb + (size_t)bh * NN * 32;
    const short* VBH = VT + (size_t)bh * 48 * 32 * 32;

    f32x16 acc, zf16;
    #pragma unroll
    for (int r = 0; r < 16; ++r) { acc[r] = 0.f; zf16[r] = 0.f; }
    float l_run = 0.f;

    int pi = w;
    int kb = 0, ra = -1, rb = -1;
    bf16x8 kf0c = {}, kf1c = {}, vf0c = {}, vf1c = {};
    if (pi < ntiles) {
        tiledesc(pi, kb, ra, rb);
        kf0c = *(const bf16x8*)(KBH + (size_t)(kb + l31) * 32 + 8 * gb);
        kf1c = *(const bf16x8*)(KBH + (size_t)(kb + l31) * 32 + 16 + 8 * gb);
        vf0c = *(const bf16x8*)(VBH + (size_t)((kb >> 5) * 32 + l31) * 32 + 8 * gb);
        vf1c = *(const bf16x8*)(VBH + (size_t)((kb >> 5) * 32 + l31) * 32 + 16 + 8 * gb);
    }
    while (pi < ntiles) {
        const int pn = pi + 4;
        int kbn, ran, rbn;
        tiledesc(pn < ntiles ? pn : pi, kbn, ran, rbn);
        const bf16x8 kf0n = *(const bf16x8*)(KBH + (size_t)(kbn + l31) * 32 + 8 * gb);
        const bf16x8 kf1n = *(const bf16x8*)(KBH + (size_t)(kbn + l31) * 32 + 16 + 8 * gb);
        const bf16x8 vf0n = *(const bf16x8*)(VBH + (size_t)((kbn >> 5) * 32 + l31) * 32 + 8 * gb);
        const bf16x8 vf1n = *(const bf16x8*)(VBH + (size_t)((kbn >> 5) * 32 + l31) * 32 + 16 + 8 * gb);

        const int rt_l = qh ? rb : ra;
        const int hk2 = (kb >> 5) & 7;
        const int t0 = 2 * hk2 - hq;
        const int dh0 = t0 < 0 ? -t0 : t0;
        const int t1 = t0 + 1;
        const int dh1 = t1 < 0 ? -t1 : t1;
        const bool A0 = dh0 <= rt_l, A1 = dh1 <= rt_l;
        bool dok[8];
        #pragma unroll
        for (int i = 0; i < 8; ++i) dok[i] = dwv[i] <= rt_l;

        f32x16 s = __builtin_amdgcn_mfma_f32_32x32x16_bf16(kf0c, qf0, zf16, 0, 0, 0);
        s = __builtin_amdgcn_mfma_f32_32x32x16_bf16(kf1c, qf1, s, 0, 0, 0);

        float p[16];
        #pragma unroll
        for (int r = 0; r < 16; ++r) {
            const bool ok = (r < 8 ? A0 : A1) && dok[r & 7];
            p[r] = ok ? exp2_raw(s[r]) : 0.f;   // Q pre-scaled by log2e
        }
        float ps = (((p[0] + p[1]) + (p[2] + p[3])) + ((p[4] + p[5]) + (p[6] + p[7])))
                 + (((p[8] + p[9]) + (p[10] + p[11])) + ((p[12] + p[13]) + (p[14] + p[15])));
        l_run += ps;

        unsigned u[8];
        #pragma unroll
        for (int j = 0; j < 8; ++j)
            asm("v_cvt_pk_bf16_f32 %0, %1, %2" : "=v"(u[j]) : "v"(p[2 * j]), "v"(p[2 * j + 1]));
        asm volatile("v_permlane32_swap_b32 %0, %1" : "+v"(u[0]), "+v"(u[2]));
        asm volatile("v_permlane32_swap_b32 %0, %1" : "+v"(u[1]), "+v"(u[3]));
        asm volatile("v_permlane32_swap_b32 %0, %1" : "+v"(u[4]), "+v"(u[6]));
        asm volatile("v_permlane32_swap_b32 %0, %1" : "+v"(u[5]), "+v"(u[7]));
        const int4 b1i = { (int)u[0], (int)u[1], (int)u[2], (int)u[3] };
        const int4 b2i = { (int)u[4], (int)u[5], (int)u[6], (int)u[7] };
        const bf16x8 pb1 = __builtin_bit_cast(bf16x8, b1i);
        const bf16x8 pb2 = __builtin_bit_cast(bf16x8, b2i);

        acc = __builtin_amdgcn_mfma_f32_32x32x16_bf16(vf0c, pb1, acc, 0, 0, 0);
        acc = __builtin_amdgcn_mfma_f32_32x32x16_bf16(vf1c, pb2, acc, 0, 0, 0);

        pi = pn; kb = kbn; ra = ran; rb = rbn;
        kf0c = kf0n; kf1c = kf1n; vf0c = vf0n; vf1c = vf1n;
    }

    // merge: all 4 waves participate; wave w handles output d-quarter j=w.
    sm_l[w][lane] = l_run;
    #pragma unroll
    for (int r = 0; r < 16; ++r) sm_acc[w][lane][r] = acc[r];
    __syncthreads();
    {
        const float lt = (sm_l[0][l31] + sm_l[0][l31 + 32])
                       + (sm_l[1][l31] + sm_l[1][l31 + 32])
                       + (sm_l[2][l31] + sm_l[2][l31 + 32])
                       + (sm_l[3][l31] + sm_l[3][l31 + 32]);
        const float inv = 1.f / lt;
        short* op = aob + ((size_t)(bh >> 3) * NN + qn) * CC + (bh & 7) * 32;
        short t4[4];
        #pragma unroll
        for (int s2 = 0; s2 < 4; ++s2) {
            const int r = 4 * w + s2;       // d = 8w + 4gb + s2
            const float a = sm_acc[0][lane][r] + sm_acc[1][lane][r]
                          + sm_acc[2][lane][r] + sm_acc[3][lane][r];
            t4[s2] = f2b(a * inv);
        }
        *(bf16x4*)(op + 8 * w + 4 * gb) = *(bf16x4*)t4;
    }
}

// ---------------------------------------------------------------------------
// Kernel 3: output projection + bias (R11). Wo pre-packed bf16 -> single
// bf16x8 load per fragment. 192 blocks x 4 waves; waves share n0.
// ---------------------------------------------------------------------------
__global__ __launch_bounds__(256) void gemm2_out(const short* __restrict__ aob,
                                                 const short* __restrict__ woT,
                                                 const float* __restrict__ bias,
                                                 float* __restrict__ out) {
    const int w = threadIdx.x >> 6, lane = threadIdx.x & 63;
    const int g = lane >> 4, c16 = lane & 15;
    const int n0 = (blockIdx.x & 3) * 64;
    const int mw = (blockIdx.x >> 2) * 64 + w * 16;
    f32x4 acc[4] = {};
    #pragma unroll
    for (int ks = 0; ks < 8; ++ks) {
        const int k0 = ks * 32;
        const bf16x8 a0 = *(const bf16x8*)(aob + (size_t)(mw + c16) * 256 + k0 + g * 8);
        #pragma unroll
        for (int ni = 0; ni < 4; ++ni) {
            const bf16x8 bfr = *(const bf16x8*)(woT + (size_t)(n0 + ni * 16 + c16) * 256 + k0 + g * 8);
            acc[ni] = __builtin_amdgcn_mfma_f32_16x16x32_bf16(a0, bfr, acc[ni], 0, 0, 0);
        }
    }
    #pragma unroll
    for (int ni = 0; ni < 4; ++ni) {
        const int col = n0 + ni * 16 + c16;
        const float bv = bias[col];
        #pragma unroll
        for (int r = 0; r < 4; ++r)
            out[(size_t)(mw + 4 * g + r) * 256 + col] = acc[ni][r] + bv;
    }
}

// ---------------------------------------------------------------------------
extern "C" void kernel_launch(void* const* d_in, const int* in_sizes, int n_in,
                              void* d_out, int out_size, void* d_ws, size_t ws_size,
                              hipStream_t stream) {
    const float* x    = (const float*)d_in[0];
    const float* Wqkv = (const float*)d_in[1];
    const float* Wo   = (const float*)d_in[2];
    const float* bo   = (const float*)d_in[3];
    float* out = (float*)d_out;

    short* Qb  = (short*)d_ws;                   // 786432 bf16
    short* Kb  = Qb  + 786432;                   // 786432
    short* VT  = Kb  + 786432;                   // 786432
    short* aob = VT  + 786432;                   // 786432
    short* woT = aob + 786432;                   // 65536

    gemm1_qkv<<<576, 256, 0, stream>>>(x, Wqkv, Qb, Kb, VT);
    attn_mfma32<<<768, 256, 0, stream>>>(Qb, Kb, VT, Wo, woT, aob);
    gemm2_out<<<192, 256, 0, stream>>>(aob, woT, bo, out);
}